// Round 4
// baseline (258.215 us; speedup 1.0000x reference)
//
#include <hip/hip_runtime.h>
#include <hip/hip_bf16.h>

// h = x(65536x512) @ W^T(512x256) + bias_lin ; GroupNorm(8 groups of 32)
// ; min over 256 channels -> m[b] ; out[c*B+b] = m[b] + bias[c]
//
// R4: 1024-thread persistent blocks (16 waves, 4/SIMD). Wave w owns col-tile w
// (16 channels); its W fragments live in 64 VGPRs, loaded once. K-loop is pure
// ds_read+MFMA. Epilogue: h -> swizzled LDS tile (aliased over x tile) ->
// all-thread group stats with b128 reads + 2-level shuffles (no deep swizzle
// chains). Output broadcast store fused.
#define B_ROWS 65536
#define K_DIM  512
#define EPS    1e-5f
#define MTILE  32
#define NBLK   256
#define NTILES (B_ROWS / MTILE)   // 2048
#define XSTR   520    // bf16 units; 1040B rows -> 2-way bank alias max (free)
#define HSTR   264    // fp32 units; 16B-aligned rows, chunk-XOR swizzle below

using short8  = __attribute__((ext_vector_type(8))) short;
using floatx4 = __attribute__((ext_vector_type(4))) float;

__device__ __forceinline__ unsigned short f2bf(float f) {
    unsigned u = __builtin_bit_cast(unsigned, f);
    u += 0x7FFFu + ((u >> 16) & 1u);     // RNE
    return (unsigned short)(u >> 16);
}

// Pack W (256x512 fp32) into bf16 MFMA B-fragment order:
// P[((nt*16 + kk)*64 + lane)*8 + j] = bf16(W[nt*16 + (lane&15)][kk*32 + (lane>>4)*8 + j])
__global__ __launch_bounds__(64) void pack_w(const float* __restrict__ W,
                                             unsigned short* __restrict__ P) {
    int b    = blockIdx.x;           // 0..255
    int nt   = b >> 4, kk = b & 15;
    int lane = threadIdx.x;
    int l15  = lane & 15, quad = lane >> 4;
    const float* src = W + (size_t)(nt * 16 + l15) * K_DIM + kk * 32 + quad * 8;
    short8 v;
#pragma unroll
    for (int j = 0; j < 8; ++j) v[j] = (short)f2bf(src[j]);
    *(short8*)(P + ((size_t)(nt * 16 + kk) * 64 + lane) * 8) = v;
}

__global__ __launch_bounds__(1024, 4) void fused(
    const float* __restrict__ X, const unsigned short* __restrict__ P,
    const float* __restrict__ bias_lin, const float* __restrict__ wgn,
    const float* __restrict__ bgn, const float* __restrict__ bias,
    float* __restrict__ out)
{
    __shared__ union {
        unsigned short x[MTILE * XSTR];   // 33280 B  (bf16 x tile)
        float          h[MTILE * HSTR];   // 33792 B  (fp32 h tile, swizzled)
    } S;
    __shared__ float wg_sh[256], bg_sh[256], bias_sh[256];
    __shared__ float Msh[MTILE * 8];
    __shared__ float m_sh[MTILE];

    const int tid  = threadIdx.x;
    const int wave = tid >> 6, lane = tid & 63;
    const int l15  = lane & 15, quad = lane >> 4;

    if (tid < 256) { wg_sh[tid] = wgn[tid]; bg_sh[tid] = bgn[tid]; bias_sh[tid] = bias[tid]; }

    // ---- this wave's W fragments: 16 channels x full K, 64 VGPRs, loaded once ----
    short8 bfr[16];
#pragma unroll
    for (int kk = 0; kk < 16; ++kk)
        bfr[kk] = *(const short8*)(P + (((size_t)wave * 16 + kk) * 64 + lane) * 8);

    const float bl = bias_lin[wave * 16 + l15];

    // staging geometry: 32 rows x 512 fp32, 1024 threads -> 4 float4 each
    const int sr = tid >> 5;          // row 0..31
    const int sc = tid & 31;          // float4-column base

    // stats geometry: pair p=tid>>2 -> (row=p&31, group=p>>5), part=tid&3 -> 8 ch
    const int pr   = (tid >> 2) & 31;
    const int pg   = tid >> 7;
    const int part = tid & 3;
    const int c0   = pg * 8 + part * 2;   // logical 4-float chunk index (x2)
    const int r7   = pr & 7;

    __syncthreads();
    const float bias_r0 = bias_sh[tid >> 3];
    const float bias_r1 = bias_sh[(tid >> 3) + 128];

    int t = blockIdx.x;
    float4 xq[4];
#pragma unroll
    for (int p = 0; p < 4; ++p)
        xq[p] = *(const float4*)(X + (size_t)(t * MTILE + sr) * K_DIM + (sc + 32 * p) * 4);

    for (; t < NTILES; t += NBLK) {
        // ---- stage x tile (fp32 regs -> bf16 LDS) ----
#pragma unroll
        for (int p = 0; p < 4; ++p) {
            ushort4 hx;
            hx.x = f2bf(xq[p].x); hx.y = f2bf(xq[p].y);
            hx.z = f2bf(xq[p].z); hx.w = f2bf(xq[p].w);
            *(ushort4*)(&S.x[sr * XSTR + (sc + 32 * p) * 4]) = hx;
        }
        __syncthreads();                                    // (1) stage visible

        // ---- prefetch next tile (in flight across K-loop + epilogue) ----
        int tn = t + NBLK;
        if (tn < NTILES) {
#pragma unroll
            for (int p = 0; p < 4; ++p)
                xq[p] = *(const float4*)(X + (size_t)(tn * MTILE + sr) * K_DIM + (sc + 32 * p) * 4);
        }

        // ---- K-loop: pure LDS + MFMA ----
        floatx4 acc0 = {0.f, 0.f, 0.f, 0.f};
        floatx4 acc1 = {0.f, 0.f, 0.f, 0.f};
#pragma unroll
        for (int kk = 0; kk < 16; ++kk) {
            short8 a0 = *(const short8*)&S.x[l15 * XSTR + kk * 32 + quad * 8];
            short8 a1 = *(const short8*)&S.x[(16 + l15) * XSTR + kk * 32 + quad * 8];
            acc0 = __builtin_amdgcn_mfma_f32_16x16x32_bf16(a0, bfr[kk], acc0, 0, 0, 0);
            acc1 = __builtin_amdgcn_mfma_f32_16x16x32_bf16(a1, bfr[kk], acc1, 0, 0, 0);
        }
        __syncthreads();                                    // (2) x reads done (h aliases x)

        // ---- h-write (+bias_lin), swizzled: word = row*HSTR + ((ch>>2 ^ (row&7))<<2) + (ch&3)
        {
            const int chq = (wave * 16 + l15) >> 2, chl = l15 & 3;
#pragma unroll
            for (int rt = 0; rt < 2; ++rt) {
                floatx4 a = rt ? acc1 : acc0;
#pragma unroll
                for (int reg = 0; reg < 4; ++reg) {
                    int row = rt * 16 + quad * 4 + reg;
                    S.h[row * HSTR + ((chq ^ (row & 7)) << 2) + chl] = a[reg] + bl;
                }
            }
        }
        __syncthreads();                                    // (3)

        // ---- stats: all 1024 threads; 4 threads per (row,group), 8 ch each ----
        {
            float4 v0 = *(const float4*)&S.h[pr * HSTR + (((c0)     ^ r7) << 2)];
            float4 v1 = *(const float4*)&S.h[pr * HSTR + (((c0 + 1) ^ r7) << 2)];
            float s  = (v0.x + v0.y) + (v0.z + v0.w) + (v1.x + v1.y) + (v1.z + v1.w);
            float ss = (v0.x*v0.x + v0.y*v0.y) + (v0.z*v0.z + v0.w*v0.w)
                     + (v1.x*v1.x + v1.y*v1.y) + (v1.z*v1.z + v1.w*v1.w);
            s  += __shfl_xor(s, 1);  ss += __shfl_xor(ss, 1);
            s  += __shfl_xor(s, 2);  ss += __shfl_xor(ss, 2);
            float mean = s * (1.0f / 32.0f);
            float var  = ss * (1.0f / 32.0f) - mean * mean;
            float inv  = rsqrtf(var + EPS);
            float4 w0 = *(const float4*)&wg_sh[c0 * 4];
            float4 w1 = *(const float4*)&wg_sh[c0 * 4 + 4];
            float4 b0 = *(const float4*)&bg_sh[c0 * 4];
            float4 b1 = *(const float4*)&bg_sh[c0 * 4 + 4];
            float mn = fminf(
                fminf(fminf((v0.x - mean) * inv * w0.x + b0.x,
                            (v0.y - mean) * inv * w0.y + b0.y),
                      fminf((v0.z - mean) * inv * w0.z + b0.z,
                            (v0.w - mean) * inv * w0.w + b0.w)),
                fminf(fminf((v1.x - mean) * inv * w1.x + b1.x,
                            (v1.y - mean) * inv * w1.y + b1.y),
                      fminf((v1.z - mean) * inv * w1.z + b1.z,
                            (v1.w - mean) * inv * w1.w + b1.w)));
            mn = fminf(mn, __shfl_xor(mn, 1));
            mn = fminf(mn, __shfl_xor(mn, 2));
            if (part == 0) Msh[pr * 8 + pg] = mn;
        }
        __syncthreads();                                    // (4)
        if (tid < MTILE) {
            float m0 = Msh[tid * 8 + 0];
#pragma unroll
            for (int g = 1; g < 8; ++g) m0 = fminf(m0, Msh[tid * 8 + g]);
            m_sh[tid] = m0;
        }
        __syncthreads();                                    // (5)

        // ---- broadcast store: out[c*B + t*32 + j] = m[j] + bias[c] ----
        {
            float4 mv = *(const float4*)&m_sh[(tid & 7) * 4];
            int c = tid >> 3;
            float4 o0, o1;
            o0.x = mv.x + bias_r0; o0.y = mv.y + bias_r0;
            o0.z = mv.z + bias_r0; o0.w = mv.w + bias_r0;
            o1.x = mv.x + bias_r1; o1.y = mv.y + bias_r1;
            o1.z = mv.z + bias_r1; o1.w = mv.w + bias_r1;
            *(float4*)(out + (size_t)c * B_ROWS + t * MTILE + (tid & 7) * 4) = o0;
            *(float4*)(out + (size_t)(c + 128) * B_ROWS + t * MTILE + (tid & 7) * 4) = o1;
        }
        // next stage writes S.x (aliases S.h): all h reads ended before (4). Safe.
    }
}

extern "C" void kernel_launch(void* const* d_in, const int* in_sizes, int n_in,
                              void* d_out, int out_size, void* d_ws, size_t ws_size,
                              hipStream_t stream) {
    const float* x    = (const float*)d_in[0];
    const float* w    = (const float*)d_in[1];
    const float* bl   = (const float*)d_in[2];
    const float* wg   = (const float*)d_in[3];
    const float* bg   = (const float*)d_in[4];
    const float* bias = (const float*)d_in[5];

    unsigned short* P = (unsigned short*)d_ws;     // 256 KB packed bf16 W
    float* out = (float*)d_out;

    hipLaunchKernelGGL(pack_w, dim3(256), dim3(64), 0, stream, w, P);
    hipLaunchKernelGGL(fused, dim3(NBLK), dim3(1024), 0, stream,
                       x, P, bl, wg, bg, bias, out);
}